// Round 2
// baseline (651.998 us; speedup 1.0000x reference)
//
#include <hip/hip_runtime.h>
#include <stdint.h>

// Problem constants (fixed by the reference)
#define Yn 5
#define Nn 200000
#define Gn 128
#define In 128
#define Rn 3
#define Bn 1024
#define Kn 64
#define GIn (Gn * In)      // 16384
#define Mn (Yn * Bn)       // 5120 output rows
#define KKn (Rn * Gn)      // 384 GEMM K-dim

// ws layout (fp32):
//   [0, Mn*KKn*4)            A: means  [5120][384]   7,864,320 B
//   [+Mn*KKn*4, +3*GIn*4)    Weff [3][128][128]        196,608 B
//   total 8,060,928 B

// K0: Weff[0] = sum of 3 cite matrices; Weff[1,2] = W_rel[1,2].
__global__ __launch_bounds__(256) void k_weff(const float* __restrict__ Wrel,
                                              const float* __restrict__ Wcite,
                                              float* __restrict__ Weff) {
    int idx = blockIdx.x * 256 + threadIdx.x;           // [0, 16384)
    Weff[idx]            = Wcite[idx] + Wcite[GIn + idx] + Wcite[2 * GIn + idx];
    Weff[GIn + idx]      = Wrel[GIn + idx];
    Weff[2 * GIn + idx]  = Wrel[2 * GIn + idx];
}

// K1: one wave (64-thread block) per (y,r,b) unit. Lane owns channels
// {2*lane, 2*lane+1} via float2 (512 B coalesced row loads). Neighbor
// indices preloaded one-per-lane, broadcast with __shfl; 8-way unrolled
// for memory-level parallelism. Mean written fp32 to A.
__global__ __launch_bounds__(64) void k_mean(const float2* __restrict__ emb2,
                                             const int* __restrict__ neighbors,
                                             const int* __restrict__ counts,
                                             float2* __restrict__ A2) {
    const int lane = threadIdx.x;                       // 0..63
    const int unit = blockIdx.x;                        // (y*3 + r)*1024 + b
    const int y = unit / (Rn * Bn);
    const int r = (unit >> 10) - y * Rn;
    const int b = unit & (Bn - 1);

    const int cnt = counts[unit];
    const int nl  = neighbors[(size_t)unit * Kn + lane]; // slot 'lane' index

    const float2* e = emb2 + (size_t)y * ((size_t)Nn * (Gn / 2));
    float a0 = 0.f, a1 = 0.f;
    int k = 0;
    for (; k + 8 <= cnt; k += 8) {
        float2 u0 = e[(size_t)__shfl(nl, k + 0) * (Gn / 2) + lane];
        float2 u1 = e[(size_t)__shfl(nl, k + 1) * (Gn / 2) + lane];
        float2 u2 = e[(size_t)__shfl(nl, k + 2) * (Gn / 2) + lane];
        float2 u3 = e[(size_t)__shfl(nl, k + 3) * (Gn / 2) + lane];
        float2 u4 = e[(size_t)__shfl(nl, k + 4) * (Gn / 2) + lane];
        float2 u5 = e[(size_t)__shfl(nl, k + 5) * (Gn / 2) + lane];
        float2 u6 = e[(size_t)__shfl(nl, k + 6) * (Gn / 2) + lane];
        float2 u7 = e[(size_t)__shfl(nl, k + 7) * (Gn / 2) + lane];
        a0 += u0.x + u1.x + u2.x + u3.x + u4.x + u5.x + u6.x + u7.x;
        a1 += u0.y + u1.y + u2.y + u3.y + u4.y + u5.y + u6.y + u7.y;
    }
    for (; k < cnt; ++k) {
        float2 u = e[(size_t)__shfl(nl, k) * (Gn / 2) + lane];
        a0 += u.x;
        a1 += u.y;
    }
    const float inv = 1.0f / (float)(cnt > 0 ? cnt : 1);
    // A[row = y*B + b][col pair = r*64 + lane]
    A2[(size_t)(y * Bn + b) * (KKn / 2) + r * (Gn / 2) + lane] =
        make_float2(a0 * inv, a1 * inv);
}

// K2: out[row][i] = sum_k A[row][k] * Weff[k][i].  Block = 16 rows x 128 cols.
// Thread t: col i = t&127, row-group rh = t>>7 (8 rows, 8 fp32 accs).
// A loads are wave-uniform float4 (L1 broadcast); W loads coalesced across i.
__global__ __launch_bounds__(256) void k_out(const float* __restrict__ A,
                                             const float* __restrict__ W,
                                             float* __restrict__ out) {
    const int t   = threadIdx.x;
    const int i   = t & 127;
    const int rh  = t >> 7;
    const int row0 = blockIdx.x * 16 + rh * 8;

    const float* Arow = A + (size_t)row0 * KKn;
    float acc[8];
#pragma unroll
    for (int j = 0; j < 8; ++j) acc[j] = 0.f;

#pragma unroll 2
    for (int q = 0; q < KKn / 4; ++q) {                 // 96 iters, 4 k per iter
        const float w0 = W[(4 * q + 0) * In + i];
        const float w1 = W[(4 * q + 1) * In + i];
        const float w2 = W[(4 * q + 2) * In + i];
        const float w3 = W[(4 * q + 3) * In + i];
#pragma unroll
        for (int j = 0; j < 8; ++j) {
            const float4 a = *(const float4*)(Arow + (size_t)j * KKn + 4 * q);
            acc[j] = fmaf(a.x, w0, fmaf(a.y, w1, fmaf(a.z, w2, fmaf(a.w, w3, acc[j]))));
        }
    }
#pragma unroll
    for (int j = 0; j < 8; ++j) {
        out[(size_t)(row0 + j) * In + i] = acc[j];
    }
}

extern "C" void kernel_launch(void* const* d_in, const int* in_sizes, int n_in,
                              void* d_out, int out_size, void* d_ws, size_t ws_size,
                              hipStream_t stream) {
    const float* emb      = (const float*)d_in[0];   // fp32 [Y][N][G]
    const float* Wrel     = (const float*)d_in[1];   // fp32 [3][G][I]
    const float* Wcite    = (const float*)d_in[2];   // fp32 [3][G][I]
    const int*   neighbors = (const int*)d_in[3];    // int32 [Y][R][B][K]
    const int*   counts    = (const int*)d_in[4];    // int32 [Y][R][B]
    // d_in[5] = train_year (unused; Y fixed at 5)

    float* A    = (float*)d_ws;                                   // [5120][384]
    float* Weff = (float*)((char*)d_ws + (size_t)Mn * KKn * 4);   // [3][128][128]

    k_weff<<<GIn / 256, 256, 0, stream>>>(Wrel, Wcite, Weff);
    k_mean<<<Yn * Rn * Bn, 64, 0, stream>>>((const float2*)emb, neighbors, counts,
                                            (float2*)A);
    k_out<<<Mn / 16, 256, 0, stream>>>(A, Weff, (float*)d_out);
}

// Round 3
// 622.818 us; speedup vs baseline: 1.0469x; 1.0469x over previous
//
#include <hip/hip_runtime.h>
#include <stdint.h>

// Problem constants (fixed by the reference)
#define Yn 5
#define Nn 200000
#define Gn 128
#define In 128
#define Rn 3
#define Bn 1024
#define Kn 64
#define GIn (Gn * In)      // 16384
#define Mn (Yn * Bn)       // 5120 output rows
#define KKn (Rn * Gn)      // 384 GEMM K-dim

// ws layout (fp32):
//   [0, Mn*KKn*4)            A: means  [5120][384]   7,864,320 B
//   [+Mn*KKn*4, +3*GIn*4)    Weff [3][128][128]        196,608 B

// K0: Weff[0] = sum of 3 cite matrices; Weff[1,2] = W_rel[1,2].
__global__ __launch_bounds__(256) void k_weff(const float* __restrict__ Wrel,
                                              const float* __restrict__ Wcite,
                                              float* __restrict__ Weff) {
    int idx = blockIdx.x * 256 + threadIdx.x;           // [0, 16384)
    Weff[idx]            = Wcite[idx] + Wcite[GIn + idx] + Wcite[2 * GIn + idx];
    Weff[GIn + idx]      = Wrel[GIn + idx];
    Weff[2 * GIn + idx]  = Wrel[2 * GIn + idx];
}

// K1: 4 independent units per 256-thread block (one wave per (y,r,b) unit;
// no barriers -> 32-waves/CU TLP headroom vs 16 for 64-thread blocks).
// Lane owns channels {2*lane, 2*lane+1} via float2 (512 B coalesced row
// loads). Neighbor indices preloaded one-per-lane, broadcast with __shfl.
// Tail handled as ONE masked 8-deep batch (mask is wave-uniform; padding
// slots reload nb[0] -> L1 hit) so the remainder costs 1 memory latency,
// not up to 7 serial ones.
__global__ __launch_bounds__(256) void k_mean(const float2* __restrict__ emb2,
                                              const int* __restrict__ neighbors,
                                              const int* __restrict__ counts,
                                              float2* __restrict__ A2) {
    const int lane = threadIdx.x & 63;
    const int unit = blockIdx.x * 4 + (threadIdx.x >> 6);   // (y*3 + r)*1024 + b
    const int y = unit / (Rn * Bn);
    const int r = (unit >> 10) - y * Rn;
    const int b = unit & (Bn - 1);

    const int cnt = counts[unit];
    const int nl  = neighbors[(size_t)unit * Kn + lane];    // slot 'lane' index

    const float2* e = emb2 + (size_t)y * ((size_t)Nn * (Gn / 2));
    float a0 = 0.f, a1 = 0.f;
    int k = 0;
    for (; k + 8 <= cnt; k += 8) {
        float2 u0 = e[(size_t)__shfl(nl, k + 0) * (Gn / 2) + lane];
        float2 u1 = e[(size_t)__shfl(nl, k + 1) * (Gn / 2) + lane];
        float2 u2 = e[(size_t)__shfl(nl, k + 2) * (Gn / 2) + lane];
        float2 u3 = e[(size_t)__shfl(nl, k + 3) * (Gn / 2) + lane];
        float2 u4 = e[(size_t)__shfl(nl, k + 4) * (Gn / 2) + lane];
        float2 u5 = e[(size_t)__shfl(nl, k + 5) * (Gn / 2) + lane];
        float2 u6 = e[(size_t)__shfl(nl, k + 6) * (Gn / 2) + lane];
        float2 u7 = e[(size_t)__shfl(nl, k + 7) * (Gn / 2) + lane];
        a0 += u0.x + u1.x + u2.x + u3.x + u4.x + u5.x + u6.x + u7.x;
        a1 += u0.y + u1.y + u2.y + u3.y + u4.y + u5.y + u6.y + u7.y;
    }
    const int rem = cnt - k;                                // 0..7, wave-uniform
    if (rem > 0) {
        float2 t[8];
#pragma unroll
        for (int j = 0; j < 8; ++j) {
            const int kk = (j < rem) ? (k + j) : 0;         // uniform select
            const float2 u = e[(size_t)__shfl(nl, kk) * (Gn / 2) + lane];
            t[j].x = (j < rem) ? u.x : 0.f;
            t[j].y = (j < rem) ? u.y : 0.f;
        }
        a0 += t[0].x + t[1].x + t[2].x + t[3].x + t[4].x + t[5].x + t[6].x + t[7].x;
        a1 += t[0].y + t[1].y + t[2].y + t[3].y + t[4].y + t[5].y + t[6].y + t[7].y;
    }
    const float inv = 1.0f / (float)(cnt > 0 ? cnt : 1);
    // A[row = y*B + b][col pair = r*64 + lane]
    A2[(size_t)(y * Bn + b) * (KKn / 2) + r * (Gn / 2) + lane] =
        make_float2(a0 * inv, a1 * inv);
}

// K2: out[row][i] = sum_k A[row][k] * Weff[k][i].  Block = 8 rows x 128 cols
// (640 blocks -> ~2.5 waves/SIMD vs 1.25 before). A tile staged through LDS
// (12.3 KB, ds_read_b128 at wave-uniform addr = broadcast, conflict-free),
// halving per-iter VMEM. W loads coalesced across i.
#define ROWS_PER_BLK 8
__global__ __launch_bounds__(256) void k_out(const float* __restrict__ A,
                                             const float* __restrict__ W,
                                             float* __restrict__ out) {
    __shared__ float As[ROWS_PER_BLK * KKn];                // 8*384*4 = 12288 B
    const int t    = threadIdx.x;
    const int row0 = blockIdx.x * ROWS_PER_BLK;

    // stage A: 8*384 = 3072 floats = 768 float4, 256 threads -> 3 iters
    {
        const float4* src = (const float4*)(A + (size_t)row0 * KKn);
        float4* dst = (float4*)As;
#pragma unroll
        for (int j = 0; j < 3; ++j) dst[t + 256 * j] = src[t + 256 * j];
    }
    __syncthreads();

    const int i  = t & 127;
    const int rh = t >> 7;                                  // rows rh*4 .. rh*4+3
    float acc[4] = {0.f, 0.f, 0.f, 0.f};

#pragma unroll 2
    for (int q = 0; q < KKn / 4; ++q) {                     // 96 iters, 4 k each
        const float w0 = W[(4 * q + 0) * In + i];
        const float w1 = W[(4 * q + 1) * In + i];
        const float w2 = W[(4 * q + 2) * In + i];
        const float w3 = W[(4 * q + 3) * In + i];
#pragma unroll
        for (int j = 0; j < 4; ++j) {
            const float4 a = *(const float4*)(As + (rh * 4 + j) * KKn + 4 * q);
            acc[j] = fmaf(a.x, w0, fmaf(a.y, w1, fmaf(a.z, w2, fmaf(a.w, w3, acc[j]))));
        }
    }
#pragma unroll
    for (int j = 0; j < 4; ++j) {
        out[(size_t)(row0 + rh * 4 + j) * In + i] = acc[j];
    }
}

extern "C" void kernel_launch(void* const* d_in, const int* in_sizes, int n_in,
                              void* d_out, int out_size, void* d_ws, size_t ws_size,
                              hipStream_t stream) {
    const float* emb       = (const float*)d_in[0];   // fp32 [Y][N][G]
    const float* Wrel      = (const float*)d_in[1];   // fp32 [3][G][I]
    const float* Wcite     = (const float*)d_in[2];   // fp32 [3][G][I]
    const int*   neighbors = (const int*)d_in[3];     // int32 [Y][R][B][K]
    const int*   counts    = (const int*)d_in[4];     // int32 [Y][R][B]
    // d_in[5] = train_year (unused; Y fixed at 5)

    float* A    = (float*)d_ws;                                   // [5120][384]
    float* Weff = (float*)((char*)d_ws + (size_t)Mn * KKn * 4);   // [3][128][128]

    k_weff<<<GIn / 256, 256, 0, stream>>>(Wrel, Wcite, Weff);
    k_mean<<<(Yn * Rn * Bn) / 4, 256, 0, stream>>>((const float2*)emb, neighbors,
                                                   counts, (float2*)A);
    k_out<<<Mn / ROWS_PER_BLK, 256, 0, stream>>>(A, Weff, (float*)d_out);
}